// Round 2
// baseline (179.369 us; speedup 1.0000x reference)
//
#include <hip/hip_runtime.h>
#include <hip/hip_bf16.h>

#define NSTEP 50
#define S51 51
#define HID 128
#define MT 64                  // rows per tile
#define BPB 16                 // batch elems per block (block owns them -> no global atomics)
#define RPB (BPB * S51)        // 816 valid rows per block
#define NTILE 13               // ceil(816/64): 832 rows, 16 masked (1.9% waste)
#define GRID (16384 / BPB)     // 1024 blocks
#define BLOCK 256              // 4 waves; wave mi owns hidden slice [mi*32, mi*32+32)

typedef __attribute__((ext_vector_type(4))) float floatx4;
typedef __attribute__((ext_vector_type(16))) float floatx16;
typedef __attribute__((ext_vector_type(8))) __bf16 bf16x8;

// 4 x f32 -> 4 packed fp8 e4m3 bytes (v_cvt_pk_fp8_f32, gfx950 OCP e4m3fn)
__device__ __forceinline__ unsigned pk4_fp8(float v0, float v1, float v2, float v3) {
    unsigned r = (unsigned)__builtin_amdgcn_cvt_pk_fp8_f32(v0, v1, 0, false);   // bytes 0,1
    r = (unsigned)__builtin_amdgcn_cvt_pk_fp8_f32(v2, v3, (int)r, true);        // bytes 2,3
    return r;
}

// Swizzled fp8 activation layout: row-major 64x128 bytes, rows = 16 chunks of 8B,
// phys_chunk = chunk ^ (row & 15). R16: since row*128, (row&15)<<3 and chunk<<3
// occupy disjoint/XOR-compatible bits, addr = BASE ^ (chunk<<3) with BASE
// precomputed once per lane — one v_xor per access, no per-access sw8 math.

// Register-only C-operand build (address-taken aggregates spill — R7 lesson)
__device__ __forceinline__ floatx16 ld_bias16(const float* bs, int base) {
    const floatx4 t0 = *(const floatx4*)(&bs[base]);
    const floatx4 t1 = *(const floatx4*)(&bs[base + 8]);
    const floatx4 t2 = *(const floatx4*)(&bs[base + 16]);
    const floatx4 t3 = *(const floatx4*)(&bs[base + 24]);
    floatx16 v = {t0[0], t0[1], t0[2], t0[3], t1[0], t1[1], t1[2], t1[3],
                  t2[0], t2[1], t2[2], t2[3], t3[0], t3[1], t3[2], t3[3]};
    return v;
}

// L1 (2->128) on the matrix pipe: one bf16 32x32x16 MFMA per 32x32 block
// (K holds k=0:X-weight, k=1:h-weight; bias via C). D-layout dtype-independent,
// so relu->pk4_fp8->swizzled-store matches the A2 epilogue. ts[51]=0 pads.
__device__ __forceinline__ void l1_tile(unsigned char* dst, int t,
                                        const float* tsp, const float* b1s,
                                        bf16x8 aw, float xv, __bf16 hb, float hm,
                                        int wbm, int l31, int hi, int mi) {
    const int s1 = 4 * t + (l31 >> 4);       // ss for row l31; row l31+32 is +2
    bf16x8 bx0 = {}, bx1 = {};
    bx0[0] = (__bf16)(xv * tsp[s1] * hm);     bx0[1] = hb;
    bx1[0] = (__bf16)(xv * tsp[s1 + 2] * hm); bx1[1] = hb;
    const floatx16 ci = ld_bias16(b1s, mi * 32 + 4 * hi);
    floatx16 d0 = __builtin_amdgcn_mfma_f32_32x32x16_bf16(aw, bx0, ci, 0, 0, 0);
    floatx16 d1 = __builtin_amdgcn_mfma_f32_32x32x16_bf16(aw, bx1, ci, 0, 0, 0);
#pragma unroll
    for (int g = 0; g < 4; ++g) {
        unsigned p0 = pk4_fp8(fmaxf(d0[4 * g + 0], 0.0f), fmaxf(d0[4 * g + 1], 0.0f),
                              fmaxf(d0[4 * g + 2], 0.0f), fmaxf(d0[4 * g + 3], 0.0f));
        *(unsigned*)(&dst[wbm ^ (g << 3)]) = p0;
        unsigned p1 = pk4_fp8(fmaxf(d1[4 * g + 0], 0.0f), fmaxf(d1[4 * g + 1], 0.0f),
                              fmaxf(d1[4 * g + 2], 0.0f), fmaxf(d1[4 * g + 3], 0.0f));
        *(unsigned*)(&dst[(wbm ^ (g << 3)) + 4096]) = p1;
    }
}

// R16 on top of R15 (80 us steady): counters showed MFMA 4.4k + VALU 6.8k +
// LDS 4.8k ~= 14.7k wall cycles/phase — pipes SERIALIZED by per-wave dependency
// chain + barrier lockstep. (a) L4+consume deferred one phase: c0/c1 carried in
// the same registers across the barrier (L4 reads-then-L3 overwrites -> no copy,
// no extra pressure) so ~110 VALU ops issue at phase start with zero current-
// phase deps; (b) L2+L3 fused into one BB for steady phases (4 indep MFMA
// chains, scheduler pipelines reads); (c) XOR-base LDS addressing (1 op/access).
// Register budget is the binding constraint: 64 VGPR + 64 AGPR = 128/wave at
// 4 waves/SIMD; LDS 37.9KB caps 4 blocks/CU — both saturated, don't add state.
__launch_bounds__(BLOCK, 4)
__global__ void monotonic_fused(const float* __restrict__ x, const float* __restrict__ h,
                                const float* __restrict__ w1, const float* __restrict__ b1,
                                const float* __restrict__ w2, const float* __restrict__ b2,
                                const float* __restrict__ w3, const float* __restrict__ b3,
                                const float* __restrict__ w4, const float* __restrict__ b4,
                                float* __restrict__ out) {
    __shared__ __align__(16) unsigned char A1[2][MT * HID];  // a1 fp8, 2 x 8 KB
    __shared__ __align__(16) unsigned char A2[2][MT * HID];  // a2 fp8, 2 x 8 KB
    __shared__ float b1s[HID], b2s[HID], b3s[HID], w4s[HID];
    __shared__ float fs[S51], ts[52];                        // ts[51] = 0 pads masked rows
    __shared__ float xs[BPB], hs[BPB];
    __shared__ float posum[2][4][MT];                        // parity x mi x row

    const int tid = threadIdx.x;
    const int lane = tid & 63;
    const int mi = tid >> 6;      // wave 0..3 = hidden 32-slice
    const int l31 = lane & 31;
    const int hi = lane >> 5;

    // ---- stage small tensors ----
    if (tid < HID) {
        b1s[tid] = b1[tid]; b2s[tid] = b2[tid]; b3s[tid] = b3[tid]; w4s[tid] = w4[tid];
    }
    if (tid < BPB) {
        xs[tid] = x[blockIdx.x * BPB + tid];
        hs[tid] = h[blockIdx.x * BPB + tid];
    }
    if (tid < 52) {
        if (tid < S51) {
            // Faithful port of compute_cc_weights (verified R1-R15)
            const float PI50 = 0.06283185307179586f;  // pi/50
            float acc = 1.0f;
            for (int i = 2; i <= 50; i += 2) {
                int m = (i * tid) % 100;  // exact argument reduction
                acc += (2.0f / (1.0f - (float)(i * i))) * cosf((float)m * PI50);
            }
            float ccw = acc * 0.04f * ((tid == 0 || tid == NSTEP) ? 0.5f : 1.0f);
            fs[tid] = ccw * 0.5f;                               // folds the (x-x0)*0.5 factor
            ts[tid] = (cosf((float)tid * PI50) + 1.0f) * 0.5f;  // (steps+1)/2
        } else {
            ts[51] = 0.0f;   // tile 12 rows with ss==51 read this (masked at consume)
        }
    }
    const float b4v = b4[0];
    const float hm = (hi == 0) ? 1.0f : 0.0f;   // zero the k=8..15 half of bf16 frags

    // ---- gather W2^T / W3^T A-operand fp8 fragments (coalesced over l31) ----
    long w2f[8], w3f[8];
    {
        const int irow = mi * 32 + l31;
#pragma unroll
        for (int kc = 0; kc < 8; ++kc) {
            const int kb = kc * 16 + hi * 8;
            unsigned lo2 = pk4_fp8(w2[(kb + 0) * HID + irow], w2[(kb + 1) * HID + irow],
                                   w2[(kb + 2) * HID + irow], w2[(kb + 3) * HID + irow]);
            unsigned hi2 = pk4_fp8(w2[(kb + 4) * HID + irow], w2[(kb + 5) * HID + irow],
                                   w2[(kb + 6) * HID + irow], w2[(kb + 7) * HID + irow]);
            w2f[kc] = (long)(((unsigned long long)hi2 << 32) | lo2);
            unsigned lo3 = pk4_fp8(w3[(kb + 0) * HID + irow], w3[(kb + 1) * HID + irow],
                                   w3[(kb + 2) * HID + irow], w3[(kb + 3) * HID + irow]);
            unsigned hi3 = pk4_fp8(w3[(kb + 4) * HID + irow], w3[(kb + 5) * HID + irow],
                                   w3[(kb + 6) * HID + irow], w3[(kb + 7) * HID + irow]);
            w3f[kc] = (long)(((unsigned long long)hi3 << 32) | lo3);
        }
    }
    // ---- W1 bf16 A-frag (once): lane j=mi*32+l31; k=0 -> w1[0][j], k=1 -> w1[1][j] ----
    bf16x8 aw = {};
    {
        const int j = mi * 32 + l31;
        aw[0] = (__bf16)(w1[j] * hm);
        aw[1] = (__bf16)(w1[HID + j] * hm);
    }
    __syncthreads();

    // per-lane constants: row remap lr = ss*16 + bbl  =>  bbl = r&15 fixed per lane
    const float xv = xs[l31 & 15];
    const __bf16 hb = (__bf16)(hs[l31 & 15] * hm);
    float accq = 0.0f;            // wave-0 per-lane quadrature accumulator (bbl = tid&15)

    // XOR-addressing bases (disjoint-bit decomposition of sw8, verified above):
    // reads:  addr(kc,hi-half) = rbh ^ (kc<<4)   [+4096 for row l31+32]
    // writes: addr(g)          = wbm ^ (g<<3)    [+4096 for row l31+32]
    const int rb  = l31 * HID + ((l31 & 15) << 3);
    const int rbh = rb ^ (hi << 3);
    const int wbm = (rb + 4 * hi) ^ (mi << 5);

    // ---- L1 for tile 0 -> A1[0] ----
    l1_tile(A1[0], 0, ts, b1s, aw, xv, hb, hm, wbm, l31, hi, mi);
    __syncthreads();

    floatx16 c0 = {}, c1 = {};    // L3 outputs; live across one barrier (deferred L4)

    // Phase schedule (tile t): L1@t-1 -> L2@t -> pack@t -> L3@t+1 -> L4@t+2 -> consume@t+3
    for (int s = 0; s <= NTILE + 2; ++s) {
        const int pa = s & 1, pb = pa ^ 1;
        floatx16 a0, a1;

        // ---- deferred L4 on c(tile s-2) (regs, computed phase s-1) -> posum[pa] ----
        if (s >= 2 && s <= NTILE + 1) {
            float p0 = 0.0f, p1 = 0.0f;
#pragma unroll
            for (int g = 0; g < 4; ++g) {
                const floatx4 w4v = *(const floatx4*)(&w4s[mi * 32 + 8 * g + 4 * hi]);
#pragma unroll
                for (int rr = 0; rr < 4; ++rr) {
                    p0 = fmaf(fmaxf(c0[4 * g + rr], 0.0f), w4v[rr], p0);
                    p1 = fmaf(fmaxf(c1[4 * g + rr], 0.0f), w4v[rr], p1);
                }
            }
            p0 += __shfl_xor(p0, 32);
            p1 += __shfl_xor(p1, 32);
            if (hi == 0) {
                posum[pa][mi][l31] = p0;
                posum[pa][mi][l31 + 32] = p1;
            }
        }
        // ---- consume tile s-3 partials (posum[pb], written phase s-1) ----
        if (s >= 3 && tid < MT) {
            int lr = (s - 3) * MT + tid;
            if (lr < RPB) {
                float u = posum[pb][0][tid] + posum[pb][1][tid] + posum[pb][2][tid]
                        + posum[pb][3][tid] + b4v;
                float dz = u > 0.0f ? u + 1.0f : __expf(u);  // elu(u)+1
                accq += dz * fs[lr >> 4];                    // ss = lr>>4
            }
        }
        // ---- MFMA chains: fused L2(tile s) + L3(tile s-1), 4 independent chains ----
        if (s >= 1 && s < NTILE) {
            const floatx16 ci2 = ld_bias16(b2s, mi * 32 + 4 * hi);
            const floatx16 ci3 = ld_bias16(b3s, mi * 32 + 4 * hi);
            long f0 = *(const long*)(&A1[pa][rbh]);
            long f1 = *(const long*)(&A1[pa][rbh + 4096]);
            long g0 = *(const long*)(&A2[pb][rbh]);
            long g1 = *(const long*)(&A2[pb][rbh + 4096]);
            a0 = __builtin_amdgcn_mfma_f32_32x32x16_fp8_fp8(w2f[0], f0, ci2, 0, 0, 0);
            a1 = __builtin_amdgcn_mfma_f32_32x32x16_fp8_fp8(w2f[0], f1, ci2, 0, 0, 0);
            c0 = __builtin_amdgcn_mfma_f32_32x32x16_fp8_fp8(w3f[0], g0, ci3, 0, 0, 0);
            c1 = __builtin_amdgcn_mfma_f32_32x32x16_fp8_fp8(w3f[0], g1, ci3, 0, 0, 0);
#pragma unroll
            for (int kc = 1; kc < 8; ++kc) {
                f0 = *(const long*)(&A1[pa][rbh ^ (kc << 4)]);
                f1 = *(const long*)(&A1[pa][(rbh ^ (kc << 4)) + 4096]);
                g0 = *(const long*)(&A2[pb][rbh ^ (kc << 4)]);
                g1 = *(const long*)(&A2[pb][(rbh ^ (kc << 4)) + 4096]);
                a0 = __builtin_amdgcn_mfma_f32_32x32x16_fp8_fp8(w2f[kc], f0, a0, 0, 0, 0);
                a1 = __builtin_amdgcn_mfma_f32_32x32x16_fp8_fp8(w2f[kc], f1, a1, 0, 0, 0);
                c0 = __builtin_amdgcn_mfma_f32_32x32x16_fp8_fp8(w3f[kc], g0, c0, 0, 0, 0);
                c1 = __builtin_amdgcn_mfma_f32_32x32x16_fp8_fp8(w3f[kc], g1, c1, 0, 0, 0);
            }
        } else if (s < NTILE) {            // s == 0: L2 only
            const floatx16 ci2 = ld_bias16(b2s, mi * 32 + 4 * hi);
            long f0 = *(const long*)(&A1[pa][rbh]);
            long f1 = *(const long*)(&A1[pa][rbh + 4096]);
            a0 = __builtin_amdgcn_mfma_f32_32x32x16_fp8_fp8(w2f[0], f0, ci2, 0, 0, 0);
            a1 = __builtin_amdgcn_mfma_f32_32x32x16_fp8_fp8(w2f[0], f1, ci2, 0, 0, 0);
#pragma unroll
            for (int kc = 1; kc < 8; ++kc) {
                f0 = *(const long*)(&A1[pa][rbh ^ (kc << 4)]);
                f1 = *(const long*)(&A1[pa][(rbh ^ (kc << 4)) + 4096]);
                a0 = __builtin_amdgcn_mfma_f32_32x32x16_fp8_fp8(w2f[kc], f0, a0, 0, 0, 0);
                a1 = __builtin_amdgcn_mfma_f32_32x32x16_fp8_fp8(w2f[kc], f1, a1, 0, 0, 0);
            }
        } else if (s <= NTILE) {           // s == NTILE: L3 only
            const floatx16 ci3 = ld_bias16(b3s, mi * 32 + 4 * hi);
            long g0 = *(const long*)(&A2[pb][rbh]);
            long g1 = *(const long*)(&A2[pb][rbh + 4096]);
            c0 = __builtin_amdgcn_mfma_f32_32x32x16_fp8_fp8(w3f[0], g0, ci3, 0, 0, 0);
            c1 = __builtin_amdgcn_mfma_f32_32x32x16_fp8_fp8(w3f[0], g1, ci3, 0, 0, 0);
#pragma unroll
            for (int kc = 1; kc < 8; ++kc) {
                g0 = *(const long*)(&A2[pb][rbh ^ (kc << 4)]);
                g1 = *(const long*)(&A2[pb][(rbh ^ (kc << 4)) + 4096]);
                c0 = __builtin_amdgcn_mfma_f32_32x32x16_fp8_fp8(w3f[kc], g0, c0, 0, 0, 0);
                c1 = __builtin_amdgcn_mfma_f32_32x32x16_fp8_fp8(w3f[kc], g1, c1, 0, 0, 0);
            }
        }
        // ---- epilogue: relu(a) -> A2[pa] fp8 ----
        if (s < NTILE) {
#pragma unroll
            for (int g = 0; g < 4; ++g) {
                unsigned p0 = pk4_fp8(fmaxf(a0[4 * g + 0], 0.0f), fmaxf(a0[4 * g + 1], 0.0f),
                                      fmaxf(a0[4 * g + 2], 0.0f), fmaxf(a0[4 * g + 3], 0.0f));
                *(unsigned*)(&A2[pa][wbm ^ (g << 3)]) = p0;
                unsigned p1 = pk4_fp8(fmaxf(a1[4 * g + 0], 0.0f), fmaxf(a1[4 * g + 1], 0.0f),
                                      fmaxf(a1[4 * g + 2], 0.0f), fmaxf(a1[4 * g + 3], 0.0f));
                *(unsigned*)(&A2[pa][(wbm ^ (g << 3)) + 4096]) = p1;
            }
        }
        // ---- L1-MFMA for tile s+1 -> A1[pb] (A1[pb] last read in phase s-1) ----
        if (s + 1 < NTILE) {
            l1_tile(A1[pb], s + 1, ts, b1s, aw, xv, hb, hm, wbm, l31, hi, mi);
        }
        __syncthreads();
    }

    // cross-lane reduce (lanes l, l^16, l^32, l^48 share bbl = l&15) and write out
    if (tid < MT) {
        accq += __shfl_xor(accq, 16);
        accq += __shfl_xor(accq, 32);
        if (tid < BPB) out[blockIdx.x * BPB + tid] = hs[tid] + accq * xs[tid];
    }
}

extern "C" void kernel_launch(void* const* d_in, const int* in_sizes, int n_in,
                              void* d_out, int out_size, void* d_ws, size_t ws_size,
                              hipStream_t stream) {
    const float* x  = (const float*)d_in[0];
    const float* h  = (const float*)d_in[1];
    const float* w1 = (const float*)d_in[2];
    const float* b1 = (const float*)d_in[3];
    const float* w2 = (const float*)d_in[4];
    const float* b2 = (const float*)d_in[5];
    const float* w3 = (const float*)d_in[6];
    const float* b3 = (const float*)d_in[7];
    const float* w4 = (const float*)d_in[8];
    const float* b4 = (const float*)d_in[9];
    float* out = (float*)d_out;

    monotonic_fused<<<GRID, BLOCK, 0, stream>>>(x, h, w1, b1, w2, b2, w3, b3, w4, b4, out);
}

// Round 3
// 131.343 us; speedup vs baseline: 1.3657x; 1.3657x over previous
//
#include <hip/hip_runtime.h>
#include <hip/hip_bf16.h>

#define NSTEP 50
#define S51 51
#define HID 128
#define MT 64                  // rows per tile
#define BPB 16                 // batch elems per block (block owns them -> no global atomics)
#define RPB (BPB * S51)        // 816 valid rows per block
#define NTILE 13               // ceil(816/64): 832 rows, 16 masked (1.9% waste)
#define GRID (16384 / BPB)     // 1024 blocks
#define BLOCK 256              // 4 waves; wave mi owns hidden slice [mi*32, mi*32+32)

typedef __attribute__((ext_vector_type(4))) float floatx4;
typedef __attribute__((ext_vector_type(16))) float floatx16;
typedef __attribute__((ext_vector_type(8))) __bf16 bf16x8;

// 4 x f32 -> 4 packed fp8 e4m3 bytes (v_cvt_pk_fp8_f32, gfx950 OCP e4m3fn)
__device__ __forceinline__ unsigned pk4_fp8(float v0, float v1, float v2, float v3) {
    unsigned r = (unsigned)__builtin_amdgcn_cvt_pk_fp8_f32(v0, v1, 0, false);   // bytes 0,1
    r = (unsigned)__builtin_amdgcn_cvt_pk_fp8_f32(v2, v3, (int)r, true);        // bytes 2,3
    return r;
}

// Swizzled fp8 activation layout: row-major 64x128 bytes, rows = 16 chunks of 8B,
// phys_chunk = chunk ^ (row & 15). XOR-base form (R16-verified, R17-kept):
//   base rb  = l31*128 + ((l31&15)<<3)            (disjoint bits -> '+' ok)
//   reads:  addr = (rb ^ (hi<<3)) ^ (kc<<4)  [+4096 for row l31+32]
//   writes: addr = ((rb + 4*hi) ^ (mi<<5)) ^ (g<<3)  [+4096 for row l31+32]
// One v_xor per access instead of per-access sw8 math (~140 VALU ops/phase saved).

// Register-only C-operand build (address-taken aggregates spill — R7 lesson)
__device__ __forceinline__ floatx16 ld_bias16(const float* bs, int base) {
    const floatx4 t0 = *(const floatx4*)(&bs[base]);
    const floatx4 t1 = *(const floatx4*)(&bs[base + 8]);
    const floatx4 t2 = *(const floatx4*)(&bs[base + 16]);
    const floatx4 t3 = *(const floatx4*)(&bs[base + 24]);
    floatx16 v = {t0[0], t0[1], t0[2], t0[3], t1[0], t1[1], t1[2], t1[3],
                  t2[0], t2[1], t2[2], t2[3], t3[0], t3[1], t3[2], t3[3]};
    return v;
}

// L1 (2->128) on the matrix pipe: one bf16 32x32x16 MFMA per 32x32 block.
// R17: bias b1 folded into k=2 (aw[2]=b1[j], bx[2]=1*hm), C-in = zero ->
// no per-phase ld_bias16 for L1, b1s LDS array deleted. ts[51]=0 pads.
__device__ __forceinline__ void l1_tile(unsigned char* dst, int t,
                                        const float* tsp,
                                        bf16x8 aw, float xv, __bf16 hb, float hm,
                                        int wbm, int l31, int hi, int mi) {
    const int s1 = 4 * t + (l31 >> 4);       // ss for row l31; row l31+32 is +2
    bf16x8 bx0 = {}, bx1 = {};
    bx0[0] = (__bf16)(xv * tsp[s1] * hm);     bx0[1] = hb;  bx0[2] = (__bf16)hm;
    bx1[0] = (__bf16)(xv * tsp[s1 + 2] * hm); bx1[1] = hb;  bx1[2] = (__bf16)hm;
    const floatx16 zz = {};
    floatx16 d0 = __builtin_amdgcn_mfma_f32_32x32x16_bf16(aw, bx0, zz, 0, 0, 0);
    floatx16 d1 = __builtin_amdgcn_mfma_f32_32x32x16_bf16(aw, bx1, zz, 0, 0, 0);
#pragma unroll
    for (int g = 0; g < 4; ++g) {
        unsigned p0 = pk4_fp8(fmaxf(d0[4 * g + 0], 0.0f), fmaxf(d0[4 * g + 1], 0.0f),
                              fmaxf(d0[4 * g + 2], 0.0f), fmaxf(d0[4 * g + 3], 0.0f));
        *(unsigned*)(&dst[wbm ^ (g << 3)]) = p0;
        unsigned p1 = pk4_fp8(fmaxf(d1[4 * g + 0], 0.0f), fmaxf(d1[4 * g + 1], 0.0f),
                              fmaxf(d1[4 * g + 2], 0.0f), fmaxf(d1[4 * g + 3], 0.0f));
        *(unsigned*)(&dst[(wbm ^ (g << 3)) + 4096]) = p1;
    }
}

// R17 = R15 revert (proven 80 us steady) + XOR addressing + L1 bias-in-k.
// R16 post-mortem: FETCH 8->242MB, WRITE 17.7->55MB = SCRATCH SPILLS — the
// loop-carried c0/c1 + fused 4-chain MFMA block exceeded the exact 128-reg/wave
// fit (64 VGPR + 64 AGPR at 4 waves/SIMD). Deferral also buys little: the 4
// resident blocks/CU have independent barriers -> cross-block interleave
// already overlaps pipes. LEDGER: defer/fusion (R16, spills), LDS-bytes (R9),
// occupancy (R10/R11 — reg file caps 16 waves/CU regardless of LDS), VALU
// packing (R13/R14) closed. Do NOT extend floatx16 live ranges across barriers.
__launch_bounds__(BLOCK, 4)
__global__ void monotonic_fused(const float* __restrict__ x, const float* __restrict__ h,
                                const float* __restrict__ w1, const float* __restrict__ b1,
                                const float* __restrict__ w2, const float* __restrict__ b2,
                                const float* __restrict__ w3, const float* __restrict__ b3,
                                const float* __restrict__ w4, const float* __restrict__ b4,
                                float* __restrict__ out) {
    __shared__ __align__(16) unsigned char A1[2][MT * HID];  // a1 fp8, 2 x 8 KB
    __shared__ __align__(16) unsigned char A2[2][MT * HID];  // a2 fp8, 2 x 8 KB
    __shared__ float b2s[HID], b3s[HID], w4s[HID];
    __shared__ float fs[S51], ts[52];                        // ts[51] = 0 pads masked rows
    __shared__ float xs[BPB], hs[BPB];
    __shared__ float posum[2][4][MT];                        // parity x mi x row

    const int tid = threadIdx.x;
    const int lane = tid & 63;
    const int mi = tid >> 6;      // wave 0..3 = hidden 32-slice
    const int l31 = lane & 31;
    const int hi = lane >> 5;

    // ---- stage small tensors ----
    if (tid < HID) {
        b2s[tid] = b2[tid]; b3s[tid] = b3[tid]; w4s[tid] = w4[tid];
    }
    if (tid < BPB) {
        xs[tid] = x[blockIdx.x * BPB + tid];
        hs[tid] = h[blockIdx.x * BPB + tid];
    }
    if (tid < 52) {
        if (tid < S51) {
            // Faithful port of compute_cc_weights (verified R1-R16)
            const float PI50 = 0.06283185307179586f;  // pi/50
            float acc = 1.0f;
            for (int i = 2; i <= 50; i += 2) {
                int m = (i * tid) % 100;  // exact argument reduction
                acc += (2.0f / (1.0f - (float)(i * i))) * cosf((float)m * PI50);
            }
            float ccw = acc * 0.04f * ((tid == 0 || tid == NSTEP) ? 0.5f : 1.0f);
            fs[tid] = ccw * 0.5f;                               // folds the (x-x0)*0.5 factor
            ts[tid] = (cosf((float)tid * PI50) + 1.0f) * 0.5f;  // (steps+1)/2
        } else {
            ts[51] = 0.0f;   // tile 12 rows with ss==51 read this (masked at consume)
        }
    }
    const float b4v = b4[0];
    const float hm = (hi == 0) ? 1.0f : 0.0f;   // zero the k=8..15 half of bf16 frags

    // ---- gather W2^T / W3^T A-operand fp8 fragments (coalesced over l31) ----
    long w2f[8], w3f[8];
    {
        const int irow = mi * 32 + l31;
#pragma unroll
        for (int kc = 0; kc < 8; ++kc) {
            const int kb = kc * 16 + hi * 8;
            unsigned lo2 = pk4_fp8(w2[(kb + 0) * HID + irow], w2[(kb + 1) * HID + irow],
                                   w2[(kb + 2) * HID + irow], w2[(kb + 3) * HID + irow]);
            unsigned hi2 = pk4_fp8(w2[(kb + 4) * HID + irow], w2[(kb + 5) * HID + irow],
                                   w2[(kb + 6) * HID + irow], w2[(kb + 7) * HID + irow]);
            w2f[kc] = (long)(((unsigned long long)hi2 << 32) | lo2);
            unsigned lo3 = pk4_fp8(w3[(kb + 0) * HID + irow], w3[(kb + 1) * HID + irow],
                                   w3[(kb + 2) * HID + irow], w3[(kb + 3) * HID + irow]);
            unsigned hi3 = pk4_fp8(w3[(kb + 4) * HID + irow], w3[(kb + 5) * HID + irow],
                                   w3[(kb + 6) * HID + irow], w3[(kb + 7) * HID + irow]);
            w3f[kc] = (long)(((unsigned long long)hi3 << 32) | lo3);
        }
    }
    // ---- W1+b1 bf16 A-frag (once): k=0 -> w1[0][j], k=1 -> w1[1][j], k=2 -> b1[j] ----
    bf16x8 aw = {};
    {
        const int j = mi * 32 + l31;
        aw[0] = (__bf16)(w1[j] * hm);
        aw[1] = (__bf16)(w1[HID + j] * hm);
        aw[2] = (__bf16)(b1[j] * hm);
    }
    __syncthreads();

    // per-lane constants: row remap lr = ss*16 + bbl  =>  bbl = r&15 fixed per lane
    const float xv = xs[l31 & 15];
    const __bf16 hb = (__bf16)(hs[l31 & 15] * hm);
    float accq = 0.0f;            // wave-0 per-lane quadrature accumulator (bbl = tid&15)

    // XOR-addressing bases (disjoint-bit decomposition of sw8, R16-verified)
    const int rb  = l31 * HID + ((l31 & 15) << 3);
    const int rbh = rb ^ (hi << 3);
    const int wbm = (rb + 4 * hi) ^ (mi << 5);

    // ---- L1 for tile 0 -> A1[0] ----
    l1_tile(A1[0], 0, ts, aw, xv, hb, hm, wbm, l31, hi, mi);
    __syncthreads();

    for (int s = 0; s <= NTILE; ++s) {
        const int pa = s & 1, pb = pa ^ 1;
        floatx16 a0, a1, c0, c1;

        // ---- L2-MFMA on tile s (read A1[pa]); bias as C of peeled MFMA ----
        if (s < NTILE) {
            const floatx16 ci = ld_bias16(b2s, mi * 32 + 4 * hi);
            long f0 = *(const long*)(&A1[pa][rbh]);
            long f1 = *(const long*)(&A1[pa][rbh + 4096]);
            a0 = __builtin_amdgcn_mfma_f32_32x32x16_fp8_fp8(w2f[0], f0, ci, 0, 0, 0);
            a1 = __builtin_amdgcn_mfma_f32_32x32x16_fp8_fp8(w2f[0], f1, ci, 0, 0, 0);
#pragma unroll
            for (int kc = 1; kc < 8; ++kc) {
                f0 = *(const long*)(&A1[pa][rbh ^ (kc << 4)]);
                f1 = *(const long*)(&A1[pa][(rbh ^ (kc << 4)) + 4096]);
                a0 = __builtin_amdgcn_mfma_f32_32x32x16_fp8_fp8(w2f[kc], f0, a0, 0, 0, 0);
                a1 = __builtin_amdgcn_mfma_f32_32x32x16_fp8_fp8(w2f[kc], f1, a1, 0, 0, 0);
            }
        }
        // ---- L3-MFMA on tile s-1 (read A2[pb]) — independent chain, overlaps L2 ----
        if (s >= 1) {
            const floatx16 ci = ld_bias16(b3s, mi * 32 + 4 * hi);
            long g0 = *(const long*)(&A2[pb][rbh]);
            long g1 = *(const long*)(&A2[pb][rbh + 4096]);
            c0 = __builtin_amdgcn_mfma_f32_32x32x16_fp8_fp8(w3f[0], g0, ci, 0, 0, 0);
            c1 = __builtin_amdgcn_mfma_f32_32x32x16_fp8_fp8(w3f[0], g1, ci, 0, 0, 0);
#pragma unroll
            for (int kc = 1; kc < 8; ++kc) {
                g0 = *(const long*)(&A2[pb][rbh ^ (kc << 4)]);
                g1 = *(const long*)(&A2[pb][(rbh ^ (kc << 4)) + 4096]);
                c0 = __builtin_amdgcn_mfma_f32_32x32x16_fp8_fp8(w3f[kc], g0, c0, 0, 0, 0);
                c1 = __builtin_amdgcn_mfma_f32_32x32x16_fp8_fp8(w3f[kc], g1, c1, 0, 0, 0);
            }
        }
        // ---- consume tile s-2 partials into registers (no atomics: bbl == tid&15) ----
        if (s >= 2 && tid < MT) {
            int lr = (s - 2) * MT + tid;
            if (lr < RPB) {
                float u = posum[pa][0][tid] + posum[pa][1][tid] + posum[pa][2][tid]
                        + posum[pa][3][tid] + b4v;
                float dz = u > 0.0f ? u + 1.0f : __expf(u);  // elu(u)+1
                accq += dz * fs[lr >> 4];                    // ss = lr>>4
            }
        }
        // ---- epilogue: relu(a) -> A2[pa] fp8 ----
        if (s < NTILE) {
#pragma unroll
            for (int g = 0; g < 4; ++g) {
                unsigned p0 = pk4_fp8(fmaxf(a0[4 * g + 0], 0.0f), fmaxf(a0[4 * g + 1], 0.0f),
                                      fmaxf(a0[4 * g + 2], 0.0f), fmaxf(a0[4 * g + 3], 0.0f));
                *(unsigned*)(&A2[pa][wbm ^ (g << 3)]) = p0;
                unsigned p1 = pk4_fp8(fmaxf(a1[4 * g + 0], 0.0f), fmaxf(a1[4 * g + 1], 0.0f),
                                      fmaxf(a1[4 * g + 2], 0.0f), fmaxf(a1[4 * g + 3], 0.0f));
                *(unsigned*)(&A2[pa][(wbm ^ (g << 3)) + 4096]) = p1;
            }
        }
        // ---- fused L4 for tile s-1 -> posum[pb] (plain stores) ----
        if (s >= 1) {
            float p0 = 0.0f, p1 = 0.0f;
#pragma unroll
            for (int g = 0; g < 4; ++g) {
                const floatx4 w4v = *(const floatx4*)(&w4s[mi * 32 + 8 * g + 4 * hi]);
#pragma unroll
                for (int rr = 0; rr < 4; ++rr) {
                    p0 = fmaf(fmaxf(c0[4 * g + rr], 0.0f), w4v[rr], p0);
                    p1 = fmaf(fmaxf(c1[4 * g + rr], 0.0f), w4v[rr], p1);
                }
            }
            p0 += __shfl_xor(p0, 32);
            p1 += __shfl_xor(p1, 32);
            if (hi == 0) {
                posum[pb][mi][l31] = p0;
                posum[pb][mi][l31 + 32] = p1;
            }
        }
        // ---- L1-MFMA for tile s+1 -> A1[pb] (A1[pb] last read in phase s-1) ----
        if (s + 1 < NTILE) {
            l1_tile(A1[pb], s + 1, ts, aw, xv, hb, hm, wbm, l31, hi, mi);
        }
        __syncthreads();
    }

    // final consume: tile NTILE-1 partials, then cross-lane reduce (lanes l, l^16,
    // l^32, l^48 share bbl = l&15) and write out — no LDS atomics anywhere.
    if (tid < MT) {
        int lr = (NTILE - 1) * MT + tid;
        if (lr < RPB) {
            const int pf = (NTILE - 1) & 1;
            float u = posum[pf][0][tid] + posum[pf][1][tid] + posum[pf][2][tid]
                    + posum[pf][3][tid] + b4v;
            float dz = u > 0.0f ? u + 1.0f : __expf(u);
            accq += dz * fs[lr >> 4];
        }
        accq += __shfl_xor(accq, 16);
        accq += __shfl_xor(accq, 32);
        if (tid < BPB) out[blockIdx.x * BPB + tid] = hs[tid] + accq * xs[tid];
    }
}

extern "C" void kernel_launch(void* const* d_in, const int* in_sizes, int n_in,
                              void* d_out, int out_size, void* d_ws, size_t ws_size,
                              hipStream_t stream) {
    const float* x  = (const float*)d_in[0];
    const float* h  = (const float*)d_in[1];
    const float* w1 = (const float*)d_in[2];
    const float* b1 = (const float*)d_in[3];
    const float* w2 = (const float*)d_in[4];
    const float* b2 = (const float*)d_in[5];
    const float* w3 = (const float*)d_in[6];
    const float* b3 = (const float*)d_in[7];
    const float* w4 = (const float*)d_in[8];
    const float* b4 = (const float*)d_in[9];
    float* out = (float*)d_out;

    monotonic_fused<<<GRID, BLOCK, 0, stream>>>(x, h, w1, b1, w2, b2, w3, b3, w4, b4, out);
}

// Round 4
// 129.052 us; speedup vs baseline: 1.3899x; 1.0178x over previous
//
#include <hip/hip_runtime.h>
#include <hip/hip_bf16.h>

#define NSTEP 50
#define S51 51
#define HID 128
#define MT 64                  // rows per tile
#define BPB 16                 // batch elems per block (block owns them -> no global atomics)
#define RPB (BPB * S51)        // 816 valid rows per block
#define NTILE 13               // ceil(816/64): 832 rows, 16 masked (1.9% waste)
#define GRID (16384 / BPB)     // 1024 blocks
#define BLOCK 256              // 4 waves; wave mi owns hidden slice [mi*32, mi*32+32)

typedef __attribute__((ext_vector_type(4))) float floatx4;
typedef __attribute__((ext_vector_type(16))) float floatx16;
typedef __attribute__((ext_vector_type(8))) __bf16 bf16x8;

// 4 x f32 -> 4 packed fp8 e4m3 bytes (v_cvt_pk_fp8_f32, gfx950 OCP e4m3fn)
__device__ __forceinline__ unsigned pk4_fp8(float v0, float v1, float v2, float v3) {
    unsigned r = (unsigned)__builtin_amdgcn_cvt_pk_fp8_f32(v0, v1, 0, false);   // bytes 0,1
    r = (unsigned)__builtin_amdgcn_cvt_pk_fp8_f32(v2, v3, (int)r, true);        // bytes 2,3
    return r;
}

// Swizzled fp8 activation layout: row-major 64x128 bytes, rows = 16 chunks of 8B,
// phys_chunk = chunk ^ (row & 15). XOR-base form (R16-verified):
//   base rb  = l31*128 + ((l31&15)<<3)            (disjoint bits -> '+' ok)
//   reads:  addr = (rb ^ (hi<<3)) ^ (kc<<4)  [+4096 for row l31+32]
//   writes: addr = ((rb + 4*hi) ^ (mi<<5)) ^ (g<<3)  [+4096 for row l31+32]

// Register-only C-operand build (address-taken aggregates spill — R7 lesson)
__device__ __forceinline__ floatx16 ld_bias16(const float* bs, int base) {
    const floatx4 t0 = *(const floatx4*)(&bs[base]);
    const floatx4 t1 = *(const floatx4*)(&bs[base + 8]);
    const floatx4 t2 = *(const floatx4*)(&bs[base + 16]);
    const floatx4 t3 = *(const floatx4*)(&bs[base + 24]);
    floatx16 v = {t0[0], t0[1], t0[2], t0[3], t1[0], t1[1], t1[2], t1[3],
                  t2[0], t2[1], t2[2], t2[3], t3[0], t3[1], t3[2], t3[3]};
    return v;
}

// L1 (2->128) on the matrix pipe: one bf16 32x32x16 MFMA per 32x32 block.
// Bias b1 folded into k=2 (aw[2]=b1[j], bx[2]=1*hm), C-in = zero (R17-verified).
// ts[51..55]=0 pads masked rows and the dummy tile-13 build at s=12.
__device__ __forceinline__ void l1_tile(unsigned char* dst, int t,
                                        const float* tsp,
                                        bf16x8 aw, float xv, __bf16 hb, float hm,
                                        int wbm, int l31, int hi, int mi) {
    const int s1 = 4 * t + (l31 >> 4);       // ss for row l31; row l31+32 is +2
    bf16x8 bx0 = {}, bx1 = {};
    bx0[0] = (__bf16)(xv * tsp[s1] * hm);     bx0[1] = hb;  bx0[2] = (__bf16)hm;
    bx1[0] = (__bf16)(xv * tsp[s1 + 2] * hm); bx1[1] = hb;  bx1[2] = (__bf16)hm;
    const floatx16 zz = {};
    floatx16 d0 = __builtin_amdgcn_mfma_f32_32x32x16_bf16(aw, bx0, zz, 0, 0, 0);
    floatx16 d1 = __builtin_amdgcn_mfma_f32_32x32x16_bf16(aw, bx1, zz, 0, 0, 0);
#pragma unroll
    for (int g = 0; g < 4; ++g) {
        unsigned p0 = pk4_fp8(fmaxf(d0[4 * g + 0], 0.0f), fmaxf(d0[4 * g + 1], 0.0f),
                              fmaxf(d0[4 * g + 2], 0.0f), fmaxf(d0[4 * g + 3], 0.0f));
        *(unsigned*)(&dst[wbm ^ (g << 3)]) = p0;
        unsigned p1 = pk4_fp8(fmaxf(d1[4 * g + 0], 0.0f), fmaxf(d1[4 * g + 1], 0.0f),
                              fmaxf(d1[4 * g + 2], 0.0f), fmaxf(d1[4 * g + 3], 0.0f));
        *(unsigned*)(&dst[(wbm ^ (g << 3)) + 4096]) = p1;
    }
}

// R18: template<PA> phase with COMPILE-TIME parity. R17's runtime parity made
// A2[pa]/A2[pb] alias-ambiguous -> pack ds_writes ordered before L3 ds_reads,
// and separate if-BBs blocked all cross-block scheduling -> per-wave MFMA burst
// then VALU burst, barrier-locked across all 16 waves/CU (explains MfmaUtil 30
// + VALUBusy 47, neither saturated). Literal A2[0]/A2[1] are provably disjoint
// and the steady body (phases 2..12) is one straight-line BB: consume -> L2 ->
// pack -> L3 -> L4 -> L1, so the scheduler can overlap pack VALU with L3 MFMA.
// Pack-before-L3 also kills a/c accumulator co-liveness (R16's spill cause).
// LEDGER: R16 defer/fuse-with-runtime-parity (spills), R9 LDS-bytes, R10/R11
// occupancy (reg file + LDS both cap at 16 waves/CU; 96-reg config still lands
// in the 128-bucket -> no occupancy lever), R13/R14 packed-f32 VALU (not
// double-rate on CDNA4). Spill guard: FETCH_SIZE must stay ~1.9 MB.
template<int PA, bool CONS, bool L2P, bool L3P, bool L1P>
__device__ __forceinline__ void phase(int s,
        unsigned char (&A1)[2][MT * HID], unsigned char (&A2)[2][MT * HID],
        float (&posum)[2][4][MT],
        const float* b2s, const float* b3s, const float* w4s,
        const float* fs, const float* ts,
        float& accq, const long (&w2f)[8], const long (&w3f)[8],
        bf16x8 aw, float xv, __bf16 hb, float hm, float b4v,
        int rbh, int wbm, int tid, int l31, int hi, int mi) {
    constexpr int PB = PA ^ 1;
    // ---- consume tile s-2 partials (posum[PA], written phase s-1; lr<RPB
    //      guaranteed for s<=13 here — only the final epilogue needs the mask) ----
    if (CONS) {
        if (tid < MT) {
            int lr = (s - 2) * MT + tid;
            float u = posum[PA][0][tid] + posum[PA][1][tid] + posum[PA][2][tid]
                    + posum[PA][3][tid] + b4v;
            float dz = u > 0.0f ? u + 1.0f : __expf(u);  // elu(u)+1
            accq += dz * fs[lr >> 4];                    // ss = lr>>4
        }
    }
    // ---- L2-MFMA on tile s (read A1[PA]) + fp8 pack -> A2[PA] ----
    if (L2P) {
        const floatx16 ci = ld_bias16(b2s, mi * 32 + 4 * hi);
        long f0 = *(const long*)(&A1[PA][rbh]);
        long f1 = *(const long*)(&A1[PA][rbh + 4096]);
        floatx16 a0 = __builtin_amdgcn_mfma_f32_32x32x16_fp8_fp8(w2f[0], f0, ci, 0, 0, 0);
        floatx16 a1 = __builtin_amdgcn_mfma_f32_32x32x16_fp8_fp8(w2f[0], f1, ci, 0, 0, 0);
#pragma unroll
        for (int kc = 1; kc < 8; ++kc) {
            f0 = *(const long*)(&A1[PA][rbh ^ (kc << 4)]);
            f1 = *(const long*)(&A1[PA][(rbh ^ (kc << 4)) + 4096]);
            a0 = __builtin_amdgcn_mfma_f32_32x32x16_fp8_fp8(w2f[kc], f0, a0, 0, 0, 0);
            a1 = __builtin_amdgcn_mfma_f32_32x32x16_fp8_fp8(w2f[kc], f1, a1, 0, 0, 0);
        }
#pragma unroll
        for (int g = 0; g < 4; ++g) {
            unsigned p0 = pk4_fp8(fmaxf(a0[4 * g + 0], 0.0f), fmaxf(a0[4 * g + 1], 0.0f),
                                  fmaxf(a0[4 * g + 2], 0.0f), fmaxf(a0[4 * g + 3], 0.0f));
            *(unsigned*)(&A2[PA][wbm ^ (g << 3)]) = p0;
            unsigned p1 = pk4_fp8(fmaxf(a1[4 * g + 0], 0.0f), fmaxf(a1[4 * g + 1], 0.0f),
                                  fmaxf(a1[4 * g + 2], 0.0f), fmaxf(a1[4 * g + 3], 0.0f));
            *(unsigned*)(&A2[PA][(wbm ^ (g << 3)) + 4096]) = p1;
        }
    }
    // ---- L3-MFMA on tile s-1 (read A2[PB] — literal-disjoint from pack's A2[PA])
    //      + fused L4 -> posum[PB] ----
    if (L3P) {
        const floatx16 ci = ld_bias16(b3s, mi * 32 + 4 * hi);
        long g0 = *(const long*)(&A2[PB][rbh]);
        long g1 = *(const long*)(&A2[PB][rbh + 4096]);
        floatx16 c0 = __builtin_amdgcn_mfma_f32_32x32x16_fp8_fp8(w3f[0], g0, ci, 0, 0, 0);
        floatx16 c1 = __builtin_amdgcn_mfma_f32_32x32x16_fp8_fp8(w3f[0], g1, ci, 0, 0, 0);
#pragma unroll
        for (int kc = 1; kc < 8; ++kc) {
            g0 = *(const long*)(&A2[PB][rbh ^ (kc << 4)]);
            g1 = *(const long*)(&A2[PB][(rbh ^ (kc << 4)) + 4096]);
            c0 = __builtin_amdgcn_mfma_f32_32x32x16_fp8_fp8(w3f[kc], g0, c0, 0, 0, 0);
            c1 = __builtin_amdgcn_mfma_f32_32x32x16_fp8_fp8(w3f[kc], g1, c1, 0, 0, 0);
        }
        float p0 = 0.0f, p1 = 0.0f;
#pragma unroll
        for (int g = 0; g < 4; ++g) {
            const floatx4 w4v = *(const floatx4*)(&w4s[mi * 32 + 8 * g + 4 * hi]);
#pragma unroll
            for (int rr = 0; rr < 4; ++rr) {
                p0 = fmaf(fmaxf(c0[4 * g + rr], 0.0f), w4v[rr], p0);
                p1 = fmaf(fmaxf(c1[4 * g + rr], 0.0f), w4v[rr], p1);
            }
        }
        p0 += __shfl_xor(p0, 32);
        p1 += __shfl_xor(p1, 32);
        if (hi == 0) {
            posum[PB][mi][l31] = p0;
            posum[PB][mi][l31 + 32] = p1;
        }
    }
    // ---- L1-MFMA for tile s+1 -> A1[PB] (A1[PB] last read phase s-1) ----
    if (L1P) {
        l1_tile(A1[PB], s + 1, ts, aw, xv, hb, hm, wbm, l31, hi, mi);
    }
    __syncthreads();
}

__launch_bounds__(BLOCK, 4)
__global__ void monotonic_fused(const float* __restrict__ x, const float* __restrict__ h,
                                const float* __restrict__ w1, const float* __restrict__ b1,
                                const float* __restrict__ w2, const float* __restrict__ b2,
                                const float* __restrict__ w3, const float* __restrict__ b3,
                                const float* __restrict__ w4, const float* __restrict__ b4,
                                float* __restrict__ out) {
    __shared__ __align__(16) unsigned char A1[2][MT * HID];  // a1 fp8, 2 x 8 KB
    __shared__ __align__(16) unsigned char A2[2][MT * HID];  // a2 fp8, 2 x 8 KB
    __shared__ float b2s[HID], b3s[HID], w4s[HID];
    __shared__ float fs[S51], ts[56];                        // ts[51..55]=0 pad
    __shared__ float xs[BPB], hs[BPB];
    __shared__ float posum[2][4][MT];                        // parity x mi x row

    const int tid = threadIdx.x;
    const int lane = tid & 63;
    const int mi = tid >> 6;      // wave 0..3 = hidden 32-slice
    const int l31 = lane & 31;
    const int hi = lane >> 5;

    // ---- stage small tensors ----
    if (tid < HID) {
        b2s[tid] = b2[tid]; b3s[tid] = b3[tid]; w4s[tid] = w4[tid];
    }
    if (tid < BPB) {
        xs[tid] = x[blockIdx.x * BPB + tid];
        hs[tid] = h[blockIdx.x * BPB + tid];
    }
    if (tid < 56) {
        if (tid < S51) {
            // Faithful port of compute_cc_weights (verified R1-R17)
            const float PI50 = 0.06283185307179586f;  // pi/50
            float acc = 1.0f;
            for (int i = 2; i <= 50; i += 2) {
                int m = (i * tid) % 100;  // exact argument reduction
                acc += (2.0f / (1.0f - (float)(i * i))) * cosf((float)m * PI50);
            }
            float ccw = acc * 0.04f * ((tid == 0 || tid == NSTEP) ? 0.5f : 1.0f);
            fs[tid] = ccw * 0.5f;                               // folds the (x-x0)*0.5 factor
            ts[tid] = (cosf((float)tid * PI50) + 1.0f) * 0.5f;  // (steps+1)/2
        } else {
            ts[tid] = 0.0f;   // masked rows (ss=51) and dummy tile-13 build (52..55)
        }
    }
    const float b4v = b4[0];
    const float hm = (hi == 0) ? 1.0f : 0.0f;   // zero the k=8..15 half of bf16 frags

    // ---- gather W2^T / W3^T A-operand fp8 fragments (coalesced over l31) ----
    long w2f[8], w3f[8];
    {
        const int irow = mi * 32 + l31;
#pragma unroll
        for (int kc = 0; kc < 8; ++kc) {
            const int kb = kc * 16 + hi * 8;
            unsigned lo2 = pk4_fp8(w2[(kb + 0) * HID + irow], w2[(kb + 1) * HID + irow],
                                   w2[(kb + 2) * HID + irow], w2[(kb + 3) * HID + irow]);
            unsigned hi2 = pk4_fp8(w2[(kb + 4) * HID + irow], w2[(kb + 5) * HID + irow],
                                   w2[(kb + 6) * HID + irow], w2[(kb + 7) * HID + irow]);
            w2f[kc] = (long)(((unsigned long long)hi2 << 32) | lo2);
            unsigned lo3 = pk4_fp8(w3[(kb + 0) * HID + irow], w3[(kb + 1) * HID + irow],
                                   w3[(kb + 2) * HID + irow], w3[(kb + 3) * HID + irow]);
            unsigned hi3 = pk4_fp8(w3[(kb + 4) * HID + irow], w3[(kb + 5) * HID + irow],
                                   w3[(kb + 6) * HID + irow], w3[(kb + 7) * HID + irow]);
            w3f[kc] = (long)(((unsigned long long)hi3 << 32) | lo3);
        }
    }
    // ---- W1+b1 bf16 A-frag (once): k=0 -> w1[0][j], k=1 -> w1[1][j], k=2 -> b1[j] ----
    bf16x8 aw = {};
    {
        const int j = mi * 32 + l31;
        aw[0] = (__bf16)(w1[j] * hm);
        aw[1] = (__bf16)(w1[HID + j] * hm);
        aw[2] = (__bf16)(b1[j] * hm);
    }
    __syncthreads();

    // per-lane constants: row remap lr = ss*16 + bbl  =>  bbl = r&15 fixed per lane
    const float xv = xs[l31 & 15];
    const __bf16 hb = (__bf16)(hs[l31 & 15] * hm);
    float accq = 0.0f;            // wave-0 per-lane quadrature accumulator (bbl = tid&15)

    // XOR-addressing bases (disjoint-bit decomposition of sw8, R16-verified)
    const int rb  = l31 * HID + ((l31 & 15) << 3);
    const int rbh = rb ^ (hi << 3);
    const int wbm = (rb + 4 * hi) ^ (mi << 5);

    // ---- L1 for tile 0 -> A1[0] ----
    l1_tile(A1[0], 0, ts, aw, xv, hb, hm, wbm, l31, hi, mi);
    __syncthreads();

#define PHASE_ARGS A1, A2, posum, b2s, b3s, w4s, fs, ts, accq, w2f, w3f, \
                   aw, xv, hb, hm, b4v, rbh, wbm, tid, l31, hi, mi
    // edge phases 0,1; steady fused 2..12; edge 13 (parity literal throughout)
    phase<0, false, true, false, true >(0, PHASE_ARGS);
    phase<1, false, true, true,  true >(1, PHASE_ARGS);
    for (int it = 0; it < 5; ++it) {
        phase<0, true, true, true, true>(2 + 2 * it, PHASE_ARGS);
        phase<1, true, true, true, true>(3 + 2 * it, PHASE_ARGS);
    }
    phase<0, true, true,  true, true >(12, PHASE_ARGS);
    phase<1, true, false, true, false>(13, PHASE_ARGS);
#undef PHASE_ARGS

    // final consume: tile 12 (posum[0], written by L4@13), masked rows 816..831;
    // then cross-lane reduce (lanes l, l^16, l^32, l^48 share bbl = l&15).
    if (tid < MT) {
        int lr = (NTILE - 1) * MT + tid;
        if (lr < RPB) {
            float u = posum[0][0][tid] + posum[0][1][tid] + posum[0][2][tid]
                    + posum[0][3][tid] + b4v;
            float dz = u > 0.0f ? u + 1.0f : __expf(u);
            accq += dz * fs[lr >> 4];
        }
        accq += __shfl_xor(accq, 16);
        accq += __shfl_xor(accq, 32);
        if (tid < BPB) out[blockIdx.x * BPB + tid] = hs[tid] + accq * xs[tid];
    }
}

extern "C" void kernel_launch(void* const* d_in, const int* in_sizes, int n_in,
                              void* d_out, int out_size, void* d_ws, size_t ws_size,
                              hipStream_t stream) {
    const float* x  = (const float*)d_in[0];
    const float* h  = (const float*)d_in[1];
    const float* w1 = (const float*)d_in[2];
    const float* b1 = (const float*)d_in[3];
    const float* w2 = (const float*)d_in[4];
    const float* b2 = (const float*)d_in[5];
    const float* w3 = (const float*)d_in[6];
    const float* b3 = (const float*)d_in[7];
    const float* w4 = (const float*)d_in[8];
    const float* b4 = (const float*)d_in[9];
    float* out = (float*)d_out;

    monotonic_fused<<<GRID, BLOCK, 0, stream>>>(x, h, w1, b1, w2, b2, w3, b3, w4, b4, out);
}